// Round 8
// baseline (32.896 us; speedup 1.0000x reference)
//
#include <hip/hip_runtime.h>

// B=32, C=3, IMG=256, N=65536, K=49152, JMAX=16384
#define NTOT 65536
#define CCH 3
#define BB 32
#define KK 49152
#define JMAXV 16384
#define NBLK (BB * CCH)     // 96 blocks, one per (b,c) row
#define NTHR 1024           // 16 waves
#define PITCH 257           // uints per hi-pair row (pad kills bank conflicts)
#define LDS_BYTES (128 * PITCH * 4)   // 131584 B

__device__ __forceinline__ void bfly(float& a, float& b) {
    float s = a + b, d = a - b; a = s; b = d;
}

template<int CTRL>
__device__ __forceinline__ float dppx(float w) {
    return __uint_as_float((unsigned)__builtin_amdgcn_update_dpp(
        0, (int)__float_as_uint(w), CTRL, 0xF, 0xF, true));
}

// Per-lane butterfly signs: s_m = (lane & m) ? -1 : +1; stage = fmaf(s,w,p).
struct Sg { float s1, s2, s4, s8, s16, s32; };

__device__ __forceinline__ float st1(float w, float s) {
    float p = dppx<0xB1>(w); return fmaf(s, w, p);          // quad_perm xor1
}
__device__ __forceinline__ float st2(float w, float s) {
    float p = dppx<0x4E>(w); return fmaf(s, w, p);          // quad_perm xor2
}
__device__ __forceinline__ float st4(float w, float s) {
    float p = dppx<0x141>(dppx<0x1B>(w)); return fmaf(s, w, p);  // xor3 ∘ xor7
}
__device__ __forceinline__ float st8(float w, float s) {
    float p = dppx<0x140>(dppx<0x141>(w)); return fmaf(s, w, p); // xor7 ∘ xor15
}
__device__ __forceinline__ float st16(float w, float s) {
#if __has_builtin(__builtin_amdgcn_permlane16_swap)
    unsigned u = __float_as_uint(w);
    auto r = __builtin_amdgcn_permlane16_swap(u, u, false, false);
    return fmaf(s, __uint_as_float(r[1]), __uint_as_float(r[0]));
#else
    float p = __shfl_xor(w, 16); return fmaf(s, w, p);
#endif
}
__device__ __forceinline__ float st32(float w, float s) {
#if __has_builtin(__builtin_amdgcn_permlane32_swap)
    unsigned u = __float_as_uint(w);
    auto r = __builtin_amdgcn_permlane32_swap(u, u, false, false);
    return fmaf(s, __uint_as_float(r[1]), __uint_as_float(r[0]));
#else
    float p = __shfl_xor(w, 32); return fmaf(s, w, p);
#endif
}

__device__ __forceinline__ void lane_fwht6(float& w0, float& w1, float& w2,
                                           float& w3, const Sg& g) {
    w0 = st1(w0, g.s1);  w1 = st1(w1, g.s1);  w2 = st1(w2, g.s1);  w3 = st1(w3, g.s1);
    w0 = st2(w0, g.s2);  w1 = st2(w1, g.s2);  w2 = st2(w2, g.s2);  w3 = st2(w3, g.s2);
    w0 = st4(w0, g.s4);  w1 = st4(w1, g.s4);  w2 = st4(w2, g.s4);  w3 = st4(w3, g.s4);
    w0 = st8(w0, g.s8);  w1 = st8(w1, g.s8);  w2 = st8(w2, g.s8);  w3 = st8(w3, g.s8);
    w0 = st16(w0, g.s16); w1 = st16(w1, g.s16); w2 = st16(w2, g.s16); w3 = st16(w3, g.s16);
    w0 = st32(w0, g.s32); w1 = st32(w1, g.s32); w2 = st32(w2, g.s32); w3 = st32(w3, g.s32);
}

__device__ __forceinline__ Sg mk_signs(int lane) {
    Sg g;
    g.s1  = (lane & 1)  ? -1.0f : 1.0f;
    g.s2  = (lane & 2)  ? -1.0f : 1.0f;
    g.s4  = (lane & 4)  ? -1.0f : 1.0f;
    g.s8  = (lane & 8)  ? -1.0f : 1.0f;
    g.s16 = (lane & 16) ? -1.0f : 1.0f;
    g.s32 = (lane & 32) ? -1.0f : 1.0f;
    return g;
}

__device__ __forceinline__ unsigned f2bf(float f) {
    return (__float_as_uint(f) + 0x8000u) >> 16;
}
__device__ __forceinline__ float bfLo(unsigned u) { return __uint_as_float(u << 16); }
__device__ __forceinline__ float bfHi(unsigned u) { return __uint_as_float(u & 0xFFFF0000u); }

// One block per (b,c) row. Whole row lives in LDS as bf16 between passes.
//   Pass 1: lo-FWHT of 256-float segments (lane holds lo=4l+r; one
//           float4/lane/segment). Write bf16 pairs (hi even/odd) to
//           lds[pair][lo], pitch 257 uints.
//   Pass 2: hi-FWHT in place. Wave w owns lo = w*16..w*16+15; lane l holds
//           his 4l..4l+3 via two b32 column reads (bank (2l+lo)%32, free).
//   Pass 3: gather via perm (random LDS read), scale by sing/256, store.
__global__ __launch_bounds__(NTHR, 1) void whcs_fused(
        const float* __restrict__ vec, const float* __restrict__ sing,
        const int* __restrict__ perm, float* __restrict__ out) {
    extern __shared__ unsigned lds[];     // 128 * 257 uints
    int rc   = blockIdx.x;                // b*3 + c
    int t    = threadIdx.x;
    int lane = t & 63;
    int w    = t >> 6;                    // wave 0..15
    const float* src = vec + (size_t)rc * NTOT;
    Sg g = mk_signs(lane);

    // ---- Pass 1: lo-FWHT, 8 hi-pairs per wave ----
#pragma unroll
    for (int k = 0; k < 8; ++k) {
        int pi = w * 8 + k;               // hi-pair 0..127
        const float* p0 = src + (size_t)(2 * pi) * 256 + 4 * lane;
        float4 a4 = *reinterpret_cast<const float4*>(p0);
        float4 b4 = *reinterpret_cast<const float4*>(p0 + 256);
        float a0 = a4.x, a1 = a4.y, a2 = a4.z, a3 = a4.w;
        float b0 = b4.x, b1 = b4.y, b2 = b4.z, b3 = b4.w;

        bfly(a0, a1); bfly(a2, a3);       // lo bit 0
        bfly(a0, a2); bfly(a1, a3);       // lo bit 1
        lane_fwht6(a0, a1, a2, a3, g);    // lo bits 2..7
        bfly(b0, b1); bfly(b2, b3);
        bfly(b0, b2); bfly(b1, b3);
        lane_fwht6(b0, b1, b2, b3, g);

        uint4 pk;
        pk.x = f2bf(a0) | (f2bf(b0) << 16);
        pk.y = f2bf(a1) | (f2bf(b1) << 16);
        pk.z = f2bf(a2) | (f2bf(b2) << 16);
        pk.w = f2bf(a3) | (f2bf(b3) << 16);
        *reinterpret_cast<uint4*>(&lds[pi * PITCH + 4 * lane]) = pk;
    }
    __syncthreads();

    // ---- Pass 2: hi-FWHT in place ----
#pragma unroll
    for (int m = 0; m < 16; ++m) {
        int lo = w * 16 + m;
        unsigned u0 = lds[(2 * lane    ) * PITCH + lo];   // his 4l, 4l+1
        unsigned u1 = lds[(2 * lane + 1) * PITCH + lo];   // his 4l+2, 4l+3
        float w0 = bfLo(u0), w1 = bfHi(u0), w2 = bfLo(u1), w3 = bfHi(u1);
        bfly(w0, w1); bfly(w2, w3);       // hi bit 0
        bfly(w0, w2); bfly(w1, w3);       // hi bit 1
        lane_fwht6(w0, w1, w2, w3, g);    // hi bits 2..7
        lds[(2 * lane    ) * PITCH + lo] = f2bf(w0) | (f2bf(w1) << 16);
        lds[(2 * lane + 1) * PITCH + lo] = f2bf(w2) | (f2bf(w3) << 16);
    }
    __syncthreads();

    // ---- Pass 3: perm gather + scale + store ----
    int b = rc / CCH, c = rc % CCH;
    float* outp = out + (size_t)b * KK + c;
#pragma unroll
    for (int it = 0; it < JMAXV / NTHR; ++it) {
        int jj = it * NTHR + t;
        int n  = perm[jj];                        // coalesced, L2/L3-hot
        int lo = n & 255, hi = n >> 8;
        unsigned u = lds[(hi >> 1) * PITCH + lo];
        float val  = (hi & 1) ? bfHi(u) : bfLo(u);
        outp[3 * jj] = sing[3 * jj + c] * (1.0f / 256.0f) * val;
    }
}

extern "C" void kernel_launch(void* const* d_in, const int* in_sizes, int n_in,
                              void* d_out, int out_size, void* d_ws, size_t ws_size,
                              hipStream_t stream) {
    const float* vec  = (const float*)d_in[0];
    const float* sing = (const float*)d_in[1];
    const int*   perm = (const int*)d_in[2];
    float* out = (float*)d_out;

    whcs_fused<<<NBLK, NTHR, LDS_BYTES, stream>>>(vec, sing, perm, out);
}

// Round 9
// 28.207 us; speedup vs baseline: 1.1663x; 1.1663x over previous
//
#include <hip/hip_runtime.h>

// B=32, C=3, IMG=256, N=65536, K=49152, JMAX=16384
#define NTOT 65536
#define CCH 3
#define BB 32
#define KK 49152
#define JMAXV 16384
#define K1_FWHT 768      // (b,c,hi-group) transform blocks
#define K1_TOTAL 1024    // + 256 table-build blocks
#define K2_BLOCKS 2048

struct F3 { float x, y, z; };

__device__ __forceinline__ void bfly(float& a, float& b) {
    float s = a + b, d = a - b; a = s; b = d;
}

template<int CTRL>
__device__ __forceinline__ float dppx(float w) {
    return __uint_as_float((unsigned)__builtin_amdgcn_update_dpp(
        0, (int)__float_as_uint(w), CTRL, 0xF, 0xF, true));
}

// Per-lane butterfly signs: s_m = (lane & m) ? -1 : +1; stage = fmaf(s,w,p).
struct Sg { float s1, s2, s4, s8, s16, s32; };

__device__ __forceinline__ float st1(float w, float s) {
    float p = dppx<0xB1>(w); return fmaf(s, w, p);               // quad_perm xor1
}
__device__ __forceinline__ float st2(float w, float s) {
    float p = dppx<0x4E>(w); return fmaf(s, w, p);               // quad_perm xor2
}
__device__ __forceinline__ float st4(float w, float s) {
    float p = dppx<0x141>(dppx<0x1B>(w)); return fmaf(s, w, p);  // xor3 ∘ xor7
}
__device__ __forceinline__ float st8(float w, float s) {
    float p = dppx<0x140>(dppx<0x141>(w)); return fmaf(s, w, p); // xor7 ∘ xor15
}
__device__ __forceinline__ float st16(float w, float s) {
#if __has_builtin(__builtin_amdgcn_permlane16_swap)
    unsigned u = __float_as_uint(w);
    auto r = __builtin_amdgcn_permlane16_swap(u, u, false, false);
    return fmaf(s, __uint_as_float(r[1]), __uint_as_float(r[0]));
#else
    float p = __shfl_xor(w, 16); return fmaf(s, w, p);
#endif
}
__device__ __forceinline__ float st32(float w, float s) {
#if __has_builtin(__builtin_amdgcn_permlane32_swap)
    unsigned u = __float_as_uint(w);
    auto r = __builtin_amdgcn_permlane32_swap(u, u, false, false);
    return fmaf(s, __uint_as_float(r[1]), __uint_as_float(r[0]));
#else
    float p = __shfl_xor(w, 32); return fmaf(s, w, p);
#endif
}

__device__ __forceinline__ void lane_fwht6(float& w0, float& w1, float& w2,
                                           float& w3, const Sg& g) {
    w0 = st1(w0, g.s1);  w1 = st1(w1, g.s1);  w2 = st1(w2, g.s1);  w3 = st1(w3, g.s1);
    w0 = st2(w0, g.s2);  w1 = st2(w1, g.s2);  w2 = st2(w2, g.s2);  w3 = st2(w3, g.s2);
    w0 = st4(w0, g.s4);  w1 = st4(w1, g.s4);  w2 = st4(w2, g.s4);  w3 = st4(w3, g.s4);
    w0 = st8(w0, g.s8);  w1 = st8(w1, g.s8);  w2 = st8(w2, g.s8);  w3 = st8(w3, g.s8);
    w0 = st16(w0, g.s16); w1 = st16(w1, g.s16); w2 = st16(w2, g.s16); w3 = st16(w3, g.s16);
    w0 = st32(w0, g.s32); w1 = st32(w1, g.s32); w2 = st32(w2, g.s32); w3 = st32(w3, g.s32);
}

__device__ __forceinline__ Sg mk_signs(int lane) {
    Sg g;
    g.s1  = (lane & 1)  ? -1.0f : 1.0f;
    g.s2  = (lane & 2)  ? -1.0f : 1.0f;
    g.s4  = (lane & 4)  ? -1.0f : 1.0f;
    g.s8  = (lane & 8)  ? -1.0f : 1.0f;
    g.s16 = (lane & 16) ? -1.0f : 1.0f;
    g.s32 = (lane & 32) ? -1.0f : 1.0f;
    return g;
}

__device__ __forceinline__ unsigned short f2bf(float f) {
    return (unsigned short)((__float_as_uint(f) + 0x8000u) >> 16);
}

// Bijective XCD swizzle (nwg % 8 == 0): consecutive LOGICAL blocks land on
// the same XCD so shared operand panels (vec row / mid b-plane) hit L2.
__device__ __forceinline__ int xcd_swz(int bid, int nwg) {
    int cpx = nwg >> 3;                 // chunks per XCD
    return (bid & 7) * cpx + (bid >> 3);
}

// K1: lo-FWHT of 256-float segments, output TRANSPOSED as bf16
// mid_t[b][c][lo][hi]. Lane l holds lo = 4l+r. One float4/lane per segment.
// LDS [pi][lo]: one ds_write_b128/iter (bank-uniform), b32 reads at bank=t%32
// (2 lanes/bank, free). Thread t stores row lo=t, 32 his = 64B lines.
// Tail blocks build jtab_t[lo*256+hi] = j|-1 and sp_t[3*(lo*256+hi)] =
// sing[3j..]/256 (coalesced-by-n consumption in K2).
__global__ __launch_bounds__(256) void k1_lo_t(
        const float* __restrict__ vec, unsigned short* __restrict__ midt,
        const int* __restrict__ perm, const float* __restrict__ sing,
        int* __restrict__ jtabt, float* __restrict__ spt) {
    __shared__ unsigned lds32[16 * 256];   // 16 KB
    int bx = xcd_swz(blockIdx.x, K1_TOTAL);
    int t  = threadIdx.x;
    if (bx < K1_FWHT) {
        int rc  = bx >> 3;          // b*3+c
        int hi0 = (bx & 7) * 32;
        const float* src = vec + (size_t)rc * NTOT;
        int lane = t & 63;
        int w    = t >> 6;
        Sg g = mk_signs(lane);
#pragma unroll
        for (int k = 0; k < 4; ++k) {      // 4 segment-pairs per wave
            int hi = hi0 + w * 8 + 2 * k;
            float4 a4 = *reinterpret_cast<const float4*>(src + (size_t)hi * 256 + 4 * lane);
            float4 b4 = *reinterpret_cast<const float4*>(src + (size_t)(hi + 1) * 256 + 4 * lane);
            float a0 = a4.x, a1 = a4.y, a2 = a4.z, a3 = a4.w;
            float b0 = b4.x, b1 = b4.y, b2 = b4.z, b3 = b4.w;

            bfly(a0, a1); bfly(a2, a3);           // lo bit 0
            bfly(a0, a2); bfly(a1, a3);           // lo bit 1
            lane_fwht6(a0, a1, a2, a3, g);        // lo bits 2..7
            bfly(b0, b1); bfly(b2, b3);
            bfly(b0, b2); bfly(b1, b3);
            lane_fwht6(b0, b1, b2, b3, g);

            int pi = w * 4 + k;                   // hi-pair index 0..15
            uint4 pk;
            pk.x = (unsigned)f2bf(a0) | ((unsigned)f2bf(b0) << 16);
            pk.y = (unsigned)f2bf(a1) | ((unsigned)f2bf(b1) << 16);
            pk.z = (unsigned)f2bf(a2) | ((unsigned)f2bf(b2) << 16);
            pk.w = (unsigned)f2bf(a3) | ((unsigned)f2bf(b3) << 16);
            *reinterpret_cast<uint4*>(&lds32[pi * 256 + 4 * lane]) = pk;
        }
        __syncthreads();

        // thread t: output row lo=t, 32 his = 16 uints = 4x uint4 (64B line)
        unsigned* d32 = reinterpret_cast<unsigned*>(
            midt + (size_t)rc * NTOT + (size_t)t * 256 + hi0);
#pragma unroll
        for (int q4 = 0; q4 < 4; ++q4) {
            uint4 v;
            v.x = lds32[(q4 * 4 + 0) * 256 + t];
            v.y = lds32[(q4 * 4 + 1) * 256 + t];
            v.z = lds32[(q4 * 4 + 2) * 256 + t];
            v.w = lds32[(q4 * 4 + 3) * 256 + t];
            reinterpret_cast<uint4*>(d32)[q4] = v;
        }
    } else {
        int j  = (bx - K1_FWHT) * 256 + t;
        int n  = perm[j];
        int nt = (n & 255) * 256 + (n >> 8);      // transposed index lo*256+hi
        if (j < JMAXV) {
            jtabt[nt] = j;
            F3 s = *reinterpret_cast<const F3*>(sing + 3 * j);
            F3 o;
            o.x = s.x * (1.0f / 256.0f);
            o.y = s.y * (1.0f / 256.0f);
            o.z = s.z * (1.0f / 256.0f);
            *reinterpret_cast<F3*>(spt + 3 * nt) = o;
        } else {
            jtabt[nt] = -1;
        }
    }
}

// K2: hi-FWHT straight from mid_t (coalesced, LDS-free), fused scatter.
// Wave = one (b,lo), all 3 channels. Lane l holds hi = 4l+r (uint2/lane);
// jtab_t row as int4/lane; sp_t row as 3x float4/lane (48B contiguous).
// Only the out-store itself is scattered (unavoidable).
__global__ __launch_bounds__(256) void k2_hi_scatter(
        const unsigned short* __restrict__ midt, const int* __restrict__ jtabt,
        const float* __restrict__ spt, float* __restrict__ out) {
    int gid  = xcd_swz(blockIdx.x, K2_BLOCKS) * 256 + threadIdx.x;
    int lane = gid & 63;
    int wid  = gid >> 6;          // 0..8191
    int b    = wid >> 8;
    int lo   = wid & 255;
    Sg g = mk_signs(lane);

    float v[3][4];
#pragma unroll
    for (int c = 0; c < 3; ++c) {
        const uint2* p = reinterpret_cast<const uint2*>(
            midt + ((size_t)(b * 3 + c)) * NTOT + (size_t)lo * 256);
        uint2 u = p[lane];            // his 4l..4l+3 (bf16-packed)
        float w0 = __uint_as_float(u.x << 16);
        float w1 = __uint_as_float(u.x & 0xFFFF0000u);
        float w2 = __uint_as_float(u.y << 16);
        float w3 = __uint_as_float(u.y & 0xFFFF0000u);
        bfly(w0, w1); bfly(w2, w3);        // hi bit 0
        bfly(w0, w2); bfly(w1, w3);        // hi bit 1
        lane_fwht6(w0, w1, w2, w3, g);     // hi bits 2..7
        v[c][0] = w0; v[c][1] = w1; v[c][2] = w2; v[c][3] = w3;
    }

    int4 jq = reinterpret_cast<const int4*>(jtabt + (size_t)lo * 256)[lane];
    int jj[4] = { jq.x, jq.y, jq.z, jq.w };   // j for hi = 4l+0..3

    // sp_t row for this lo: lane reads floats [12l .. 12l+11] (contiguous)
    const float4* sprow = reinterpret_cast<const float4*>(spt + (size_t)lo * 768);
    float4 s0 = sprow[3 * lane + 0];
    float4 s1 = sprow[3 * lane + 1];
    float4 s2 = sprow[3 * lane + 2];
    float sp[12] = { s0.x, s0.y, s0.z, s0.w, s1.x, s1.y, s1.z, s1.w,
                     s2.x, s2.y, s2.z, s2.w };

    float* outb = out + (size_t)b * KK;
#pragma unroll
    for (int i = 0; i < 4; ++i) {
        int j = jj[i];
        if (j >= 0) {
            F3 o;
            o.x = sp[3 * i + 0] * v[0][i];
            o.y = sp[3 * i + 1] * v[1][i];
            o.z = sp[3 * i + 2] * v[2][i];
            *reinterpret_cast<F3*>(outb + 3 * j) = o;
        }
    }
}

extern "C" void kernel_launch(void* const* d_in, const int* in_sizes, int n_in,
                              void* d_out, int out_size, void* d_ws, size_t ws_size,
                              hipStream_t stream) {
    const float* vec  = (const float*)d_in[0];
    const float* sing = (const float*)d_in[1];
    const int*   perm = (const int*)d_in[2];
    float* out = (float*)d_out;

    int*            jtabt = (int*)d_ws;                                // 256 KB
    float*          spt   = (float*)((char*)d_ws + 262144);            // 768 KB
    unsigned short* midt  = (unsigned short*)((char*)d_ws + 1048576);  // 12.6 MB bf16

    k1_lo_t<<<K1_TOTAL, 256, 0, stream>>>(vec, midt, perm, sing, jtabt, spt);
    k2_hi_scatter<<<K2_BLOCKS, 256, 0, stream>>>(midt, jtabt, spt, out);
}

// Round 10
// 25.393 us; speedup vs baseline: 1.2955x; 1.1108x over previous
//
#include <hip/hip_runtime.h>

// B=32, C=3, IMG=256, N=65536, K=49152, JMAX=16384
#define NTOT 65536
#define CCH 3
#define BB 32
#define KK 49152
#define JMAXV 16384
#define K1_FWHT 768      // (b,c,hi-group) transform blocks
#define K1_TOTAL 1024    // + 256 table-build blocks

struct F3 { float x, y, z; };

__device__ __forceinline__ void bfly(float& a, float& b) {
    float s = a + b, d = a - b; a = s; b = d;
}

// Single DPP exchange (VALU pipe)
template<int CTRL>
__device__ __forceinline__ float dppx(float w) {
    return __uint_as_float((unsigned)__builtin_amdgcn_update_dpp(
        0, (int)__float_as_uint(w), CTRL, 0xF, 0xF, true));
}

// Per-lane butterfly signs: s_m = (lane & m) ? -1 : +1.
// Every stage is then w' = p + s*w  (exact fma with +-1).
struct Sg { float s1, s2, s4, s8, s16, s32; };

// mask 1: quad_perm [1,0,3,2] = xor1
__device__ __forceinline__ float st1(float w, float s) {
    float p = dppx<0xB1>(w); return fmaf(s, w, p);
}
// mask 2: quad_perm [2,3,0,1] = xor2
__device__ __forceinline__ float st2(float w, float s) {
    float p = dppx<0x4E>(w); return fmaf(s, w, p);
}
// mask 4: quad_perm [3,2,1,0] (xor3) then row_half_mirror (xor7) => xor4
__device__ __forceinline__ float st4(float w, float s) {
    float p = dppx<0x141>(dppx<0x1B>(w)); return fmaf(s, w, p);
}
// mask 8: row_half_mirror (xor7) then row_mirror (xor15) => xor8
__device__ __forceinline__ float st8(float w, float s) {
    float p = dppx<0x140>(dppx<0x141>(w)); return fmaf(s, w, p);
}
// mask 16: permlane16_swap (VALU)
__device__ __forceinline__ float st16(float w, float s) {
#if __has_builtin(__builtin_amdgcn_permlane16_swap)
    unsigned u = __float_as_uint(w);
    auto r = __builtin_amdgcn_permlane16_swap(u, u, false, false);
    return fmaf(s, __uint_as_float(r[1]), __uint_as_float(r[0]));
#else
    float p = __shfl_xor(w, 16); return fmaf(s, w, p);
#endif
}
// mask 32: permlane32_swap (VALU)
__device__ __forceinline__ float st32(float w, float s) {
#if __has_builtin(__builtin_amdgcn_permlane32_swap)
    unsigned u = __float_as_uint(w);
    auto r = __builtin_amdgcn_permlane32_swap(u, u, false, false);
    return fmaf(s, __uint_as_float(r[1]), __uint_as_float(r[0]));
#else
    float p = __shfl_xor(w, 32); return fmaf(s, w, p);
#endif
}

// 6 lane-exchange butterfly stages (masks 1..32) on 4 values (ILP).
__device__ __forceinline__ void lane_fwht6(float& w0, float& w1, float& w2,
                                           float& w3, const Sg& g) {
    w0 = st1(w0, g.s1);  w1 = st1(w1, g.s1);  w2 = st1(w2, g.s1);  w3 = st1(w3, g.s1);
    w0 = st2(w0, g.s2);  w1 = st2(w1, g.s2);  w2 = st2(w2, g.s2);  w3 = st2(w3, g.s2);
    w0 = st4(w0, g.s4);  w1 = st4(w1, g.s4);  w2 = st4(w2, g.s4);  w3 = st4(w3, g.s4);
    w0 = st8(w0, g.s8);  w1 = st8(w1, g.s8);  w2 = st8(w2, g.s8);  w3 = st8(w3, g.s8);
    w0 = st16(w0, g.s16); w1 = st16(w1, g.s16); w2 = st16(w2, g.s16); w3 = st16(w3, g.s16);
    w0 = st32(w0, g.s32); w1 = st32(w1, g.s32); w2 = st32(w2, g.s32); w3 = st32(w3, g.s32);
}

__device__ __forceinline__ Sg mk_signs(int lane) {
    Sg g;
    g.s1  = (lane & 1)  ? -1.0f : 1.0f;
    g.s2  = (lane & 2)  ? -1.0f : 1.0f;
    g.s4  = (lane & 4)  ? -1.0f : 1.0f;
    g.s8  = (lane & 8)  ? -1.0f : 1.0f;
    g.s16 = (lane & 16) ? -1.0f : 1.0f;
    g.s32 = (lane & 32) ? -1.0f : 1.0f;
    return g;
}

__device__ __forceinline__ unsigned short f2bf(float f) {
    return (unsigned short)((__float_as_uint(f) + 0x8000u) >> 16);
}

// K1: lo-FWHT of 256-float segments, output TRANSPOSED as bf16
// mid_t[b][c][lo][hi]. Lane l holds lo = 4l+r. One float4/lane per segment.
// LDS [pi][lo]: write one ds_write_b128/iter (conflict-free), read b32 at
// bank=t%32 (2 lanes/bank, free). Thread t stores row lo=t, 32 his = 64B.
// Tail blocks build jtab_t[lo*256+hi] = j or -1.
__global__ __launch_bounds__(256) void k1_lo_t(
        const float* __restrict__ vec, unsigned short* __restrict__ midt,
        const int* __restrict__ perm, int* __restrict__ jtabt) {
    __shared__ unsigned lds32[16 * 256];   // 16 KB
    int bx = blockIdx.x, t = threadIdx.x;
    if (bx < K1_FWHT) {
        int rc  = bx >> 3;          // b*3+c
        int hi0 = (bx & 7) * 32;
        const float* src = vec + (size_t)rc * NTOT;
        int lane = t & 63;
        int w    = t >> 6;
        Sg g = mk_signs(lane);
#pragma unroll
        for (int k = 0; k < 4; ++k) {      // 4 segment-pairs per wave
            int hi = hi0 + w * 8 + 2 * k;
            float4 a4 = *reinterpret_cast<const float4*>(src + (size_t)hi * 256 + 4 * lane);
            float4 b4 = *reinterpret_cast<const float4*>(src + (size_t)(hi + 1) * 256 + 4 * lane);
            float a0 = a4.x, a1 = a4.y, a2 = a4.z, a3 = a4.w;
            float b0 = b4.x, b1 = b4.y, b2 = b4.z, b3 = b4.w;

            bfly(a0, a1); bfly(a2, a3);           // lo bit 0
            bfly(a0, a2); bfly(a1, a3);           // lo bit 1
            lane_fwht6(a0, a1, a2, a3, g);        // lo bits 2..7
            bfly(b0, b1); bfly(b2, b3);
            bfly(b0, b2); bfly(b1, b3);
            lane_fwht6(b0, b1, b2, b3, g);

            int pi = w * 4 + k;                   // hi-pair index 0..15
            uint4 pk;
            pk.x = (unsigned)f2bf(a0) | ((unsigned)f2bf(b0) << 16);
            pk.y = (unsigned)f2bf(a1) | ((unsigned)f2bf(b1) << 16);
            pk.z = (unsigned)f2bf(a2) | ((unsigned)f2bf(b2) << 16);
            pk.w = (unsigned)f2bf(a3) | ((unsigned)f2bf(b3) << 16);
            *reinterpret_cast<uint4*>(&lds32[pi * 256 + 4 * lane]) = pk;
        }
        __syncthreads();

        // thread t: output row lo=t, 32 his = 16 uints = 4x uint4 (64B line)
        unsigned* d32 = reinterpret_cast<unsigned*>(
            midt + (size_t)rc * NTOT + (size_t)t * 256 + hi0);
#pragma unroll
        for (int q4 = 0; q4 < 4; ++q4) {
            uint4 v;
            v.x = lds32[(q4 * 4 + 0) * 256 + t];
            v.y = lds32[(q4 * 4 + 1) * 256 + t];
            v.z = lds32[(q4 * 4 + 2) * 256 + t];
            v.w = lds32[(q4 * 4 + 3) * 256 + t];
            reinterpret_cast<uint4*>(d32)[q4] = v;
        }
    } else {
        int j = (bx - K1_FWHT) * 256 + t;
        int n = perm[j];
        jtabt[(n & 255) * 256 + (n >> 8)] = (j < JMAXV) ? j : -1;
    }
}

// K2: hi-FWHT straight from mid_t (coalesced, LDS-free), fused scatter.
// Wave = one (b,lo), all 3 channels. Lane l holds hi = 4l+r (uint2/lane);
// jtab row as int4/lane. hi bits 0,1 in-register, bits 2..7 lane stages.
// sing read: random 12B but only for live j, from a 192KB L2-resident
// table (measured cheaper than a coalesced n-indexed copy, R9).
__global__ __launch_bounds__(256) void k2_hi_scatter(
        const unsigned short* __restrict__ midt, const int* __restrict__ jtabt,
        const float* __restrict__ sing, float* __restrict__ out) {
    int gid  = blockIdx.x * 256 + threadIdx.x;
    int lane = gid & 63;
    int wid  = gid >> 6;          // 0..8191
    int b    = wid >> 8;
    int lo   = wid & 255;
    Sg g = mk_signs(lane);

    float v[3][4];
#pragma unroll
    for (int c = 0; c < 3; ++c) {
        const uint2* p = reinterpret_cast<const uint2*>(
            midt + ((size_t)(b * 3 + c)) * NTOT + (size_t)lo * 256);
        uint2 u = p[lane];            // his 4l..4l+3 (bf16-packed)
        float w0 = __uint_as_float(u.x << 16);
        float w1 = __uint_as_float(u.x & 0xFFFF0000u);
        float w2 = __uint_as_float(u.y << 16);
        float w3 = __uint_as_float(u.y & 0xFFFF0000u);
        bfly(w0, w1); bfly(w2, w3);        // hi bit 0
        bfly(w0, w2); bfly(w1, w3);        // hi bit 1
        lane_fwht6(w0, w1, w2, w3, g);     // hi bits 2..7
        v[c][0] = w0; v[c][1] = w1; v[c][2] = w2; v[c][3] = w3;
    }

    int4 jq = reinterpret_cast<const int4*>(jtabt + (size_t)lo * 256)[lane];
    int jj[4] = { jq.x, jq.y, jq.z, jq.w };   // j for hi = 4l+0..3

    float* outb = out + (size_t)b * KK;
#pragma unroll
    for (int i = 0; i < 4; ++i) {
        int j = jj[i];
        if (j >= 0) {
            F3 s = *reinterpret_cast<const F3*>(sing + 3 * j);
            F3 o;
            o.x = (s.x * (1.0f / 256.0f)) * v[0][i];
            o.y = (s.y * (1.0f / 256.0f)) * v[1][i];
            o.z = (s.z * (1.0f / 256.0f)) * v[2][i];
            *reinterpret_cast<F3*>(outb + 3 * j) = o;
        }
    }
}

extern "C" void kernel_launch(void* const* d_in, const int* in_sizes, int n_in,
                              void* d_out, int out_size, void* d_ws, size_t ws_size,
                              hipStream_t stream) {
    const float* vec  = (const float*)d_in[0];
    const float* sing = (const float*)d_in[1];
    const int*   perm = (const int*)d_in[2];
    float* out = (float*)d_out;

    int*            jtabt = (int*)d_ws;                               // 256 KB
    unsigned short* midt  = (unsigned short*)((char*)d_ws + 262144);  // 12.6 MB bf16

    k1_lo_t<<<K1_TOTAL, 256, 0, stream>>>(vec, midt, perm, jtabt);
    k2_hi_scatter<<<BB * 256 / 4, 256, 0, stream>>>(midt, jtabt, sing, out);
}